// Round 3
// baseline (1745.211 us; speedup 1.0000x reference)
//
#include <hip/hip_runtime.h>

#define OFFX 0.0f
#define OFFY -40.0f
#define OFFZ -3.0f
#define BNEPS 1e-3f
#define KC 32     // knn chunks over known points
#define CHUNK 512 // knn LDS chunk (known points)
#define NCH 64    // bn partial chunks
#define NG 9      // conv tap groups (3 taps each)

// ---------------- keys ----------------
__global__ void keys_k(const int* __restrict__ coords, int n, int D, int H, int W,
                       int* __restrict__ keys) {
  int i = blockIdx.x * 256 + threadIdx.x;
  if (i < n) {
    const int* c = coords + (size_t)i * 4;
    keys[i] = ((c[0] * D + c[1]) * H + c[2]) * W + c[3];
  }
}

// ---------------- neighbor tables (subm: scale=1, stride: scale=2) ----------------
__global__ void nbr_k(const int* __restrict__ coords, int np, const int* __restrict__ keys, int nk,
                      int D, int H, int W, int scale, int* __restrict__ nbr) {
  int t = blockIdx.x * 256 + threadIdx.x;
  if (t >= np * 27) return;
  int p = t / 27, k = t % 27;
  int kz = k / 9 - 1, ky = (k / 3) % 3 - 1, kx = k % 3 - 1;
  const int* c = coords + (size_t)p * 4;
  int z = c[1] * scale + kz, y = c[2] * scale + ky, x = c[3] * scale + kx;
  int r = -1;
  if (z >= 0 && z < D && y >= 0 && y < H && x >= 0 && x < W) {
    int q = ((c[0] * D + z) * H + y) * W + x;
    int lo = 0, hi = nk;
    while (lo < hi) { int m = (lo + hi) >> 1; if (keys[m] < q) lo = m + 1; else hi = m; }
    if (lo < nk && keys[lo] == q) r = lo;
  }
  nbr[t] = r;
}

// ---------------- sparse 3x3x3 conv, tap-group partials, reg-resident weights ----------------
template<int CIN, int COUT, int P>
__global__ __launch_bounds__(256) void conv_k(const float* __restrict__ feats,
                                              const int* __restrict__ nbr,
                                              const float* __restrict__ w, int n,
                                              float* __restrict__ partial, int gstride) {
  constexpr int PR = 64 / COUT;  // points sharing a wave row
  constexpr int PW = P / 4;      // points per wave
  constexpr int NI = PW / PR;    // points per thread
  int tid = threadIdx.x;
  int wave = tid >> 6, lane = tid & 63;
  int co = lane % COUT, j = lane / COUT;
  int pbase = blockIdx.x * P + wave * PW;
  int k0 = blockIdx.y * 3;
  float acc[NI];
#pragma unroll
  for (int i = 0; i < NI; i++) acc[i] = 0.f;
#pragma unroll 1
  for (int k = k0; k < k0 + 3; k++) {
    const float* wk = w + (size_t)k * (CIN * COUT) + co;
    float wcol[CIN];
#pragma unroll
    for (int c = 0; c < CIN; c++) wcol[c] = wk[(size_t)c * COUT];  // coalesced, L1-resident
#pragma unroll
    for (int i = 0; i < NI; i++) {
      int p = pbase + i * PR + j;
      if (p >= n) continue;
      int idx = nbr[(size_t)p * 27 + k];
      if (idx < 0) continue;
      const float4* fr = (const float4*)(feats + (size_t)idx * CIN);
#pragma unroll
      for (int c4 = 0; c4 < CIN / 4; c4++) {
        float4 fv = fr[c4];
        acc[i] = fmaf(fv.x, wcol[c4 * 4 + 0], acc[i]);
        acc[i] = fmaf(fv.y, wcol[c4 * 4 + 1], acc[i]);
        acc[i] = fmaf(fv.z, wcol[c4 * 4 + 2], acc[i]);
        acc[i] = fmaf(fv.w, wcol[c4 * 4 + 3], acc[i]);
      }
    }
  }
#pragma unroll
  for (int i = 0; i < NI; i++) {
    int p = pbase + i * PR + j;
    if (p < n) partial[(size_t)blockIdx.y * gstride + (size_t)p * COUT + co] = acc[i];
  }
}

// ---------------- batchnorm: sum partials + stats, then finalize+apply ----------------
__global__ void bnpart_k(const float* __restrict__ partial, int G, int gstride, int n, int C,
                         float* __restrict__ pre, float* __restrict__ stats) {
  __shared__ float l1[256], l2[256];
  int t = threadIdx.x;
  int total = n * C;
  float s1 = 0.f, s2 = 0.f;
  for (int i = blockIdx.x * 256 + t; i < total; i += NCH * 256) {
    float v = 0.f;
    for (int g = 0; g < G; g++) v += partial[(size_t)g * gstride + i];
    pre[i] = v;
    s1 += v; s2 += v * v;
  }
  l1[t] = s1; l2[t] = s2;
  for (int s = 128; s >= C; s >>= 1) {
    __syncthreads();
    if (t < s) { l1[t] += l1[t + s]; l2[t] += l2[t + s]; }
  }
  __syncthreads();
  if (t < C) {
    stats[((size_t)blockIdx.x * C + t) * 2] = l1[t];
    stats[((size_t)blockIdx.x * C + t) * 2 + 1] = l2[t];
  }
}

__global__ void bnapply_k(const float* __restrict__ pre, const float* __restrict__ stats,
                          const float* __restrict__ bnp, int n, int C, float* __restrict__ post) {
  __shared__ float sc[128];
  int t = threadIdx.x;
  if (t < C) {
    float s1 = 0.f, s2 = 0.f;
    for (int ch = 0; ch < NCH; ch++) {
      s1 += stats[((size_t)ch * C + t) * 2];
      s2 += stats[((size_t)ch * C + t) * 2 + 1];
    }
    float m = s1 / n;
    float v = s2 / n - m * m;
    float scale = bnp[t] / sqrtf(v + BNEPS);
    sc[t] = scale;
    sc[64 + t] = bnp[C + t] - m * scale;
  }
  __syncthreads();
  size_t i = (size_t)blockIdx.x * 256 + t;
  if (i < (size_t)n * C) {
    int c = (int)(i % C);
    float v = pre[i] * sc[c] + sc[64 + c];
    post[i] = v > 0.f ? v : 0.f;
  }
}

// ---------------- points_mean ----------------
__global__ void pm_k(const float* __restrict__ vf, const int* __restrict__ c0, int n0,
                     float* __restrict__ pm, float* __restrict__ out1) {
  int i = blockIdx.x * 256 + threadIdx.x;
  if (i >= n0) return;
  float b = (float)c0[(size_t)i * 4];
  float x = vf[(size_t)i * 4], y = vf[(size_t)i * 4 + 1], z = vf[(size_t)i * 4 + 2];
  pm[(size_t)i * 4] = b; pm[(size_t)i * 4 + 1] = x; pm[(size_t)i * 4 + 2] = y; pm[(size_t)i * 4 + 3] = z;
  out1[(size_t)i * 4] = b; out1[(size_t)i * 4 + 1] = x; out1[(size_t)i * 4 + 2] = y; out1[(size_t)i * 4 + 3] = z;
}

// ---------------- knn prep: world coords per known point + batch boundary ----------------
__global__ void knnprep_k(const int* __restrict__ coords, int nl, float vx, float vy, float vz,
                          float4* __restrict__ kp4, int* __restrict__ bs) {
  int i = blockIdx.x * 256 + threadIdx.x;
  if (i >= nl) return;
  const int* c = coords + (size_t)i * 4;
  kp4[i] = make_float4(OFFX + (c[3] + 0.5f) * vx,
                       OFFY + (c[2] + 0.5f) * vy,
                       OFFZ + (c[1] + 0.5f) * vz, (float)c[0]);
  if (c[0] == 0 && (i + 1 == nl || coords[(size_t)(i + 1) * 4] == 1)) bs[0] = i + 1;
}

// ---------------- 3-NN: per-chunk branchless top-3, batch-range restricted ----------------
__global__ __launch_bounds__(256) void knn_part_k(const float4* __restrict__ pm4, int n0,
                                                  const float4* __restrict__ kp4, int nl,
                                                  const int* __restrict__ bsp,
                                                  float* __restrict__ pd, int* __restrict__ pi) {
  __shared__ __align__(16) float4 kp[CHUNK];
  int t = threadIdx.x;
  int u = blockIdx.x * 256 + t;
  int bs = bsp[0];
  int per = (nl + KC - 1) / KC;
  int ks = blockIdx.y * per;
  int ke = ks + per; if (ke > nl) ke = nl;
  float ux = 0, uy = 0, uz = 0;
  int lo = 0, hi = 0;
  if (u < n0) {
    float4 up = pm4[u];
    ux = up.y; uy = up.z; uz = up.w;
    lo = (up.x == 0.f) ? 0 : bs;
    hi = (up.x == 0.f) ? bs : nl;
  }
  float d0 = 3e38f, d1 = 3e38f, d2 = 3e38f;
  int i0 = -1, i1 = -1, i2 = -1;
  for (int base = ks; base < ke; base += CHUNK) {
    int m = ke - base; if (m > CHUNK) m = CHUNK;
    __syncthreads();
    for (int i = t; i < m; i += 256) kp[i] = kp4[base + i];
    __syncthreads();
    int e0 = lo - base; if (e0 < 0) e0 = 0;
    int e1 = hi - base; if (e1 > m) e1 = m;
#define KBODY(EE) { \
      float4 q = kp[EE]; \
      float dx = ux - q.x, dy = uy - q.y, dz = uz - q.z; \
      float d = fmaf(dx, dx, fmaf(dy, dy, dz * dz)); \
      int gi = base + (EE); \
      bool lt0 = d < d0, lt1 = d < d1, lt2 = d < d2; \
      d2 = lt2 ? (lt1 ? d1 : d) : d2; \
      i2 = lt2 ? (lt1 ? i1 : gi) : i2; \
      d1 = lt1 ? (lt0 ? d0 : d) : d1; \
      i1 = lt1 ? (lt0 ? i0 : gi) : i1; \
      d0 = lt0 ? d : d0; \
      i0 = lt0 ? gi : i0; }
    int e = e0;
    for (; e + 4 <= e1; e += 4) { KBODY(e) KBODY(e + 1) KBODY(e + 2) KBODY(e + 3) }
    for (; e < e1; e++) { KBODY(e) }
#undef KBODY
  }
  if (u < n0) {
    size_t o = ((size_t)u * KC + blockIdx.y) * 3;
    pd[o] = d0; pd[o + 1] = d1; pd[o + 2] = d2;
    pi[o] = i0; pi[o + 1] = i1; pi[o + 2] = i2;
  }
}

__global__ void knn_merge_k(const float* __restrict__ pd, const int* __restrict__ pi, int n0,
                            float* __restrict__ wv, int* __restrict__ iv) {
  int u = blockIdx.x * 256 + threadIdx.x;
  if (u >= n0) return;
  float d0 = 3e38f, d1 = 3e38f, d2 = 3e38f;
  int i0 = -1, i1 = -1, i2 = -1;
  for (int c = 0; c < KC; c++) {
    size_t o = ((size_t)u * KC + c) * 3;
    for (int e = 0; e < 3; e++) {
      int gi = pi[o + e];
      if (gi < 0) continue;
      float d = pd[o + e];
      if (d < d2) {
        if (d < d1) {
          if (d < d0) { d2 = d1; i2 = i1; d1 = d0; i1 = i0; d0 = d; i0 = gi; }
          else        { d2 = d1; i2 = i1; d1 = d;  i1 = gi; }
        } else        { d2 = d;  i2 = gi; }
      }
    }
  }
  float w0 = 1.f / (d0 + 1e-8f), w1 = 1.f / (d1 + 1e-8f), w2 = 1.f / (d2 + 1e-8f);
  float s = w0 + w1 + w2;
  wv[(size_t)u * 3] = w0 / s; wv[(size_t)u * 3 + 1] = w1 / s; wv[(size_t)u * 3 + 2] = w2 / s;
  iv[(size_t)u * 3] = i0; iv[(size_t)u * 3 + 1] = i1; iv[(size_t)u * 3 + 2] = i2;
}

__global__ void interp_k(const float* __restrict__ f, int C, const float* __restrict__ wv,
                         const int* __restrict__ iv, int n0, float* __restrict__ X, int xoff) {
  int t = blockIdx.x * 256 + threadIdx.x;
  if (t >= n0 * C) return;
  int u = t / C, c = t % C;
  float r = wv[(size_t)u * 3]     * f[(size_t)iv[(size_t)u * 3]     * C + c]
          + wv[(size_t)u * 3 + 1] * f[(size_t)iv[(size_t)u * 3 + 1] * C + c]
          + wv[(size_t)u * 3 + 2] * f[(size_t)iv[(size_t)u * 3 + 2] * C + c];
  X[(size_t)u * 160 + xoff + c] = r;
}

// ---------------- extra 1x1 conv ----------------
__global__ void conv1x1_k(const float* __restrict__ f, const float* __restrict__ we, int n,
                          float* __restrict__ out) {
  int t = blockIdx.x * 256 + threadIdx.x;
  if (t >= n * 64) return;
  int p = t >> 6, co = t & 63;
  const float* fr = f + (size_t)p * 64;
  float a = 0.f;
#pragma unroll 16
  for (int ci = 0; ci < 64; ci++) a = fmaf(fr[ci], we[ci * 64 + co], a);
  out[t] = a;
}

// ---------------- dense scatter (B, 64*D3, H3, W3) ----------------
__global__ void scatter_k(const float* __restrict__ post, const int* __restrict__ c3, int n3,
                          float* __restrict__ out0) {
  int t = blockIdx.x * 256 + threadIdx.x;
  if (t >= n3 * 64) return;
  int p = t >> 6, c = t & 63;
  const int* cc = c3 + (size_t)p * 4;
  size_t o = ((((size_t)cc[0] * 64 + c) * 6 + cc[1]) * 100 + cc[2]) * 100 + cc[3];
  out0[o] = post[t];
}

// ---------------- head: pw = X @ fc_w.T ; cls/reg projections ----------------
__global__ __launch_bounds__(256) void head_k(const float* __restrict__ X,
                                              const float* __restrict__ fcw,
                                              const float* __restrict__ clsw,
                                              const float* __restrict__ regw,
                                              int n0, float* __restrict__ outc,
                                              float* __restrict__ outr) {
  __shared__ float fl[64 * 161];
  int t = threadIdx.x;
  for (int i = t; i < 64 * 160; i += 256) {
    int r = i / 160, c = i % 160;
    fl[r * 161 + c] = fcw[i];
  }
  __syncthreads();
  int wave = t >> 6, lane = t & 63;
  int u = blockIdx.x * 4 + wave;
  if (u >= n0) return;
  const float* xr = X + (size_t)u * 160;
  const float* wr = fl + (size_t)lane * 161;
  float a = 0.f;
#pragma unroll 8
  for (int i = 0; i < 160; i++) a = fmaf(xr[i], wr[i], a);
  float c = a * clsw[lane];
  float r0 = a * regw[lane], r1 = a * regw[64 + lane], r2 = a * regw[128 + lane];
  for (int off = 32; off; off >>= 1) {
    c  += __shfl_down(c, off);
    r0 += __shfl_down(r0, off);
    r1 += __shfl_down(r1, off);
    r2 += __shfl_down(r2, off);
  }
  if (lane == 0) {
    outc[u] = c;
    outr[(size_t)u * 3] = r0; outr[(size_t)u * 3 + 1] = r1; outr[(size_t)u * 3 + 2] = r2;
  }
}

// ---------------- host ----------------
extern "C" void kernel_launch(void* const* d_in, const int* in_sizes, int n_in,
                              void* d_out, int out_size, void* d_ws, size_t ws_size,
                              hipStream_t stream) {
  const float* vf  = (const float*)d_in[0];
  const int* c0 = (const int*)d_in[1];
  const int* c1 = (const int*)d_in[2];
  const int* c2 = (const int*)d_in[3];
  const int* c3 = (const int*)d_in[4];
  const float* w00 = (const float*)d_in[5];  const float* b00 = (const float*)d_in[6];
  const float* w01 = (const float*)d_in[7];  const float* b01 = (const float*)d_in[8];
  const float* wd0 = (const float*)d_in[9];  const float* bd0 = (const float*)d_in[10];
  const float* w10 = (const float*)d_in[11]; const float* b10 = (const float*)d_in[12];
  const float* w11 = (const float*)d_in[13]; const float* b11 = (const float*)d_in[14];
  const float* wd1 = (const float*)d_in[15]; const float* bd1 = (const float*)d_in[16];
  const float* w20 = (const float*)d_in[17]; const float* b20 = (const float*)d_in[18];
  const float* w21 = (const float*)d_in[19]; const float* b21 = (const float*)d_in[20];
  const float* w22 = (const float*)d_in[21]; const float* b22 = (const float*)d_in[22];
  const float* wd2 = (const float*)d_in[23]; const float* bd2 = (const float*)d_in[24];
  const float* w30 = (const float*)d_in[25]; const float* b30 = (const float*)d_in[26];
  const float* w31 = (const float*)d_in[27]; const float* b31 = (const float*)d_in[28];
  const float* w32 = (const float*)d_in[29]; const float* b32 = (const float*)d_in[30];
  const float* we  = (const float*)d_in[31]; const float* be  = (const float*)d_in[32];
  const float* fcw = (const float*)d_in[33];
  const float* clsw = (const float*)d_in[34];
  const float* regw = (const float*)d_in[35];

  int N0 = in_sizes[1] / 4, N1 = in_sizes[2] / 4, N2 = in_sizes[3] / 4, N3 = in_sizes[4] / 4;
  int maxN = N0; if (N1 > maxN) maxN = N1; if (N2 > maxN) maxN = N2; if (N3 > maxN) maxN = N3;

  auto cdiv = [](int a, int b) { return (a + b - 1) / b; };
  char* p = (char*)d_ws;
  auto alloc = [&](size_t bytes) { char* r = p; p += (bytes + 255) & ~(size_t)255; return r; };

  int* keys0 = (int*)alloc((size_t)N0 * 4);
  int* keys1 = (int*)alloc((size_t)N1 * 4);
  int* keys2 = (int*)alloc((size_t)N2 * 4);
  int* keys3 = (int*)alloc((size_t)N3 * 4);
  int* nbr0  = (int*)alloc((size_t)N0 * 27 * 4);
  int* nbrs1 = (int*)alloc((size_t)N1 * 27 * 4);
  int* nbr1  = (int*)alloc((size_t)N1 * 27 * 4);
  int* nbrs2 = (int*)alloc((size_t)N2 * 27 * 4);
  int* nbr2  = (int*)alloc((size_t)N2 * 27 * 4);
  int* nbrs3 = (int*)alloc((size_t)N3 * 27 * 4);
  int* nbr3  = (int*)alloc((size_t)N3 * 27 * 4);
  float* FA = (float*)alloc((size_t)maxN * 64 * 4);
  float* FB = (float*)alloc((size_t)maxN * 64 * 4);
  float* FC = (float*)alloc((size_t)maxN * 64 * 4);
  float* stats = (float*)alloc((size_t)NCH * 64 * 2 * 4);
  float* pd = (float*)alloc((size_t)N0 * KC * 3 * 4);
  int*   pi = (int*)alloc((size_t)N0 * KC * 3 * 4);
  float* wv = (float*)alloc((size_t)N0 * 3 * 4);
  int*   iv = (int*)alloc((size_t)N0 * 3 * 4);
  float* X  = (float*)alloc((size_t)N0 * 160 * 4);
  float* pmb = (float*)alloc((size_t)N0 * 4 * 4);
  float4* kp1 = (float4*)alloc((size_t)N1 * 16);
  float4* kp2 = (float4*)alloc((size_t)N2 * 16);
  float4* kp3 = (float4*)alloc((size_t)N3 * 16);
  int* bsA = (int*)alloc(32);  // batch-boundary per level (slots 0..2)

  float* out0 = (float*)d_out;
  float* out1 = out0 + 7680000;        // points_mean
  float* outc = out1 + (size_t)N0 * 4; // cls
  float* outr = outc + N0;             // reg
  // dense-output region doubles as conv partial-sum scratch until the final memset
  float* partial = out0;  // NG * n * COUT floats needed; max < 7.68M

  // keys + neighbor tables + knn prep
  keys_k<<<cdiv(N0, 256), 256, 0, stream>>>(c0, N0, 41, 800, 800, keys0);
  keys_k<<<cdiv(N1, 256), 256, 0, stream>>>(c1, N1, 21, 400, 400, keys1);
  keys_k<<<cdiv(N2, 256), 256, 0, stream>>>(c2, N2, 11, 200, 200, keys2);
  keys_k<<<cdiv(N3, 256), 256, 0, stream>>>(c3, N3, 6, 100, 100, keys3);
  nbr_k<<<cdiv(N0 * 27, 256), 256, 0, stream>>>(c0, N0, keys0, N0, 41, 800, 800, 1, nbr0);
  nbr_k<<<cdiv(N1 * 27, 256), 256, 0, stream>>>(c1, N1, keys0, N0, 41, 800, 800, 2, nbrs1);
  nbr_k<<<cdiv(N1 * 27, 256), 256, 0, stream>>>(c1, N1, keys1, N1, 21, 400, 400, 1, nbr1);
  nbr_k<<<cdiv(N2 * 27, 256), 256, 0, stream>>>(c2, N2, keys1, N1, 21, 400, 400, 2, nbrs2);
  nbr_k<<<cdiv(N2 * 27, 256), 256, 0, stream>>>(c2, N2, keys2, N2, 11, 200, 200, 1, nbr2);
  nbr_k<<<cdiv(N3 * 27, 256), 256, 0, stream>>>(c3, N3, keys2, N2, 11, 200, 200, 2, nbrs3);
  nbr_k<<<cdiv(N3 * 27, 256), 256, 0, stream>>>(c3, N3, keys3, N3, 6, 100, 100, 1, nbr3);
  pm_k<<<cdiv(N0, 256), 256, 0, stream>>>(vf, c0, N0, pmb, out1);
  knnprep_k<<<cdiv(N1, 256), 256, 0, stream>>>(c1, N1, 0.2f, 0.2f, 0.4f, kp1, bsA + 0);
  knnprep_k<<<cdiv(N2, 256), 256, 0, stream>>>(c2, N2, 0.4f, 0.4f, 0.8f, kp2, bsA + 1);
  knnprep_k<<<cdiv(N3, 256), 256, 0, stream>>>(c3, N3, 0.8f, 0.8f, 1.6f, kp3, bsA + 2);

  auto conv = [&](const float* fin, const int* nb, const float* wptr, int n, int cin, int cout) {
    dim3 g32(cdiv(n, 32), NG), g16(cdiv(n, 16), NG);
    bool big = n >= 4096;
    int gs = n * cout;
    if (cin == 4 && cout == 16) {
      if (big) conv_k<4, 16, 32><<<g32, 256, 0, stream>>>(fin, nb, wptr, n, partial, gs);
      else     conv_k<4, 16, 16><<<g16, 256, 0, stream>>>(fin, nb, wptr, n, partial, gs);
    } else if (cin == 16 && cout == 16) {
      if (big) conv_k<16, 16, 32><<<g32, 256, 0, stream>>>(fin, nb, wptr, n, partial, gs);
      else     conv_k<16, 16, 16><<<g16, 256, 0, stream>>>(fin, nb, wptr, n, partial, gs);
    } else if (cin == 16 && cout == 32) {
      if (big) conv_k<16, 32, 32><<<g32, 256, 0, stream>>>(fin, nb, wptr, n, partial, gs);
      else     conv_k<16, 32, 16><<<g16, 256, 0, stream>>>(fin, nb, wptr, n, partial, gs);
    } else if (cin == 32 && cout == 32) {
      if (big) conv_k<32, 32, 32><<<g32, 256, 0, stream>>>(fin, nb, wptr, n, partial, gs);
      else     conv_k<32, 32, 16><<<g16, 256, 0, stream>>>(fin, nb, wptr, n, partial, gs);
    } else if (cin == 32 && cout == 64) {
      if (big) conv_k<32, 64, 32><<<g32, 256, 0, stream>>>(fin, nb, wptr, n, partial, gs);
      else     conv_k<32, 64, 16><<<g16, 256, 0, stream>>>(fin, nb, wptr, n, partial, gs);
    } else {
      if (big) conv_k<64, 64, 32><<<g32, 256, 0, stream>>>(fin, nb, wptr, n, partial, gs);
      else     conv_k<64, 64, 16><<<g16, 256, 0, stream>>>(fin, nb, wptr, n, partial, gs);
    }
  };
  auto bnp = [&](const float* bnpar, int n, int C, float* post) {
    bnpart_k<<<NCH, 256, 0, stream>>>(partial, NG, n * C, n, C, FC, stats);
    bnapply_k<<<cdiv(n * C, 256), 256, 0, stream>>>(FC, stats, bnpar, n, C, post);
  };
  auto knn = [&](const float4* kp4, const int* bsl, int nl, const float* f, int C, int xoff) {
    knn_part_k<<<dim3(cdiv(N0, 256), KC), 256, 0, stream>>>((const float4*)pmb, N0, kp4, nl,
                                                            bsl, pd, pi);
    knn_merge_k<<<cdiv(N0, 256), 256, 0, stream>>>(pd, pi, N0, wv, iv);
    interp_k<<<cdiv(N0 * C, 256), 256, 0, stream>>>(f, C, wv, iv, N0, X, xoff);
  };

  conv(vf, nbr0, w00, N0, 4, 16);   bnp(b00, N0, 16, FA);
  conv(FA, nbr0, w01, N0, 16, 16);  bnp(b01, N0, 16, FB);
  conv(FB, nbrs1, wd0, N1, 16, 32); bnp(bd0, N1, 32, FA);
  conv(FA, nbr1, w10, N1, 32, 32);  bnp(b10, N1, 32, FB);
  conv(FB, nbr1, w11, N1, 32, 32);  bnp(b11, N1, 32, FA);
  knn(kp1, bsA + 0, N1, FA, 32, 0);
  conv(FA, nbrs2, wd1, N2, 32, 64); bnp(bd1, N2, 64, FB);
  conv(FB, nbr2, w20, N2, 64, 64);  bnp(b20, N2, 64, FA);
  conv(FA, nbr2, w21, N2, 64, 64);  bnp(b21, N2, 64, FB);
  conv(FB, nbr2, w22, N2, 64, 64);  bnp(b22, N2, 64, FA);
  knn(kp2, bsA + 1, N2, FA, 64, 32);
  conv(FA, nbrs3, wd2, N3, 64, 64); bnp(bd2, N3, 64, FB);
  conv(FB, nbr3, w30, N3, 64, 64);  bnp(b30, N3, 64, FA);
  conv(FA, nbr3, w31, N3, 64, 64);  bnp(b31, N3, 64, FB);
  conv(FB, nbr3, w32, N3, 64, 64);  bnp(b32, N3, 64, FA);
  knn(kp3, bsA + 2, N3, FA, 64, 96);

  conv1x1_k<<<cdiv(N3 * 64, 256), 256, 0, stream>>>(FA, we, N3, FC);
  bnpart_k<<<NCH, 256, 0, stream>>>(FC, 1, 0, N3, 64, FC, stats);
  bnapply_k<<<cdiv(N3 * 64, 256), 256, 0, stream>>>(FC, stats, be, N3, 64, FB);
  hipMemsetAsync(d_out, 0, (size_t)7680000 * 4, stream);
  scatter_k<<<cdiv(N3 * 64, 256), 256, 0, stream>>>(FB, c3, N3, out0);
  head_k<<<cdiv(N0, 4), 256, 0, stream>>>(X, fcw, clsw, regw, N0, outc, outr);
}

// Round 4
// 1440.296 us; speedup vs baseline: 1.2117x; 1.2117x over previous
//
#include <hip/hip_runtime.h>

#define OFFX 0.0f
#define OFFY -40.0f
#define OFFZ -3.0f
#define BNEPS 1e-3f
#define KC 32     // knn chunks over known points
#define CHUNK 512 // knn LDS chunk (known points)
#define NCH 64    // bn partial chunks
#define NG 9      // conv tap groups (3 taps each)

// ---------------- keys ----------------
__global__ void keys_k(const int* __restrict__ coords, int n, int D, int H, int W,
                       int* __restrict__ keys) {
  int i = blockIdx.x * 256 + threadIdx.x;
  if (i < n) {
    const int* c = coords + (size_t)i * 4;
    keys[i] = ((c[0] * D + c[1]) * H + c[2]) * W + c[3];
  }
}

// ---------------- neighbor tables (subm: scale=1, stride: scale=2) ----------------
__global__ void nbr_k(const int* __restrict__ coords, int np, const int* __restrict__ keys, int nk,
                      int D, int H, int W, int scale, int* __restrict__ nbr) {
  int t = blockIdx.x * 256 + threadIdx.x;
  if (t >= np * 27) return;
  int p = t / 27, k = t % 27;
  int kz = k / 9 - 1, ky = (k / 3) % 3 - 1, kx = k % 3 - 1;
  const int* c = coords + (size_t)p * 4;
  int z = c[1] * scale + kz, y = c[2] * scale + ky, x = c[3] * scale + kx;
  int r = -1;
  if (z >= 0 && z < D && y >= 0 && y < H && x >= 0 && x < W) {
    int q = ((c[0] * D + z) * H + y) * W + x;
    int lo = 0, hi = nk;
    while (lo < hi) { int m = (lo + hi) >> 1; if (keys[m] < q) lo = m + 1; else hi = m; }
    if (lo < nk && keys[lo] == q) r = lo;
  }
  nbr[t] = r;
}

// ---------------- sparse 3x3x3 conv: LDS-staged tile-GEMM, tap-group partials ----------------
// grid = (cdiv(n,64), NG). Block: 64-point tile, 3 taps. Per tap: cooperative gather of
// neighbor feature rows into LDS transposed G[c][p]; register-tile GEMM (4 pts x CO cols/thread).
template<int CIN, int COUT>
__global__ __launch_bounds__(256) void convg_k(const float* __restrict__ feats,
                                               const int* __restrict__ nbr,
                                               const float* __restrict__ w, int n,
                                               float* __restrict__ partial, int gstride) {
  constexpr int TP = 64;
  constexpr int LDP = 68;        // row stride (floats): 16B-aligned, compute-read conflict-free
  constexpr int CO = COUT / 16;  // cols per thread (16 col-groups)
  __shared__ float G[CIN * LDP];
  int tid = threadIdx.x;
  int pg = tid >> 4, cg = tid & 15;
  int p0 = blockIdx.x * TP;
  int k0 = blockIdx.y * 3;
  float acc[4][CO];
#pragma unroll
  for (int i = 0; i < 4; i++)
#pragma unroll
    for (int j = 0; j < CO; j++) acc[i][j] = 0.f;

  for (int kk = 0; kk < 3; kk++) {
    int k = k0 + kk;
    __syncthreads();
    // stage gathered rows transposed: G[c][p]
    for (int ch = tid; ch < TP * CIN / 4; ch += 256) {
      int r = ch / (CIN / 4), c4 = ch % (CIN / 4);
      int p = p0 + r;
      int idx = (p < n) ? nbr[(size_t)p * 27 + k] : -1;
      float4 fv = make_float4(0.f, 0.f, 0.f, 0.f);
      if (idx >= 0) fv = *(const float4*)(feats + (size_t)idx * CIN + c4 * 4);
      G[(c4 * 4 + 0) * LDP + r] = fv.x;
      G[(c4 * 4 + 1) * LDP + r] = fv.y;
      G[(c4 * 4 + 2) * LDP + r] = fv.z;
      G[(c4 * 4 + 3) * LDP + r] = fv.w;
    }
    __syncthreads();
    const float* wk = w + (size_t)k * CIN * COUT + cg * CO;
#pragma unroll 8
    for (int c = 0; c < CIN; c++) {
      float4 g4 = *(const float4*)&G[c * LDP + pg * 4];
      float wv[CO];
      if constexpr (CO == 4)      *(float4*)wv = *(const float4*)(wk + c * COUT);
      else if constexpr (CO == 2) *(float2*)wv = *(const float2*)(wk + c * COUT);
      else                        wv[0] = wk[c * COUT];
      float gp[4] = {g4.x, g4.y, g4.z, g4.w};
#pragma unroll
      for (int i = 0; i < 4; i++)
#pragma unroll
        for (int j = 0; j < CO; j++) acc[i][j] = fmaf(gp[i], wv[j], acc[i][j]);
    }
  }
#pragma unroll
  for (int i = 0; i < 4; i++) {
    int p = p0 + pg * 4 + i;
    if (p < n) {
      float* dst = partial + (size_t)blockIdx.y * gstride + (size_t)p * COUT + cg * CO;
      if constexpr (CO == 4)      *(float4*)dst = *(float4*)acc[i];
      else if constexpr (CO == 2) *(float2*)dst = *(float2*)acc[i];
      else                        dst[0] = acc[i][0];
    }
  }
}

// ---------------- batchnorm: sum partials + stats, then finalize+apply ----------------
__global__ void bnpart_k(const float* __restrict__ partial, int G, int gstride, int n, int C,
                         float* __restrict__ pre, float* __restrict__ stats) {
  __shared__ float l1[256], l2[256];
  int t = threadIdx.x;
  int total = n * C;
  float s1 = 0.f, s2 = 0.f;
  for (int i = blockIdx.x * 256 + t; i < total; i += NCH * 256) {
    float v = 0.f;
    for (int g = 0; g < G; g++) v += partial[(size_t)g * gstride + i];
    pre[i] = v;
    s1 += v; s2 += v * v;
  }
  l1[t] = s1; l2[t] = s2;
  for (int s = 128; s >= C; s >>= 1) {
    __syncthreads();
    if (t < s) { l1[t] += l1[t + s]; l2[t] += l2[t + s]; }
  }
  __syncthreads();
  if (t < C) {
    stats[((size_t)blockIdx.x * C + t) * 2] = l1[t];
    stats[((size_t)blockIdx.x * C + t) * 2 + 1] = l2[t];
  }
}

__global__ void bnapply_k(const float* __restrict__ pre, const float* __restrict__ stats,
                          const float* __restrict__ bnp, int n, int C, float* __restrict__ post) {
  __shared__ float sc[128];
  int t = threadIdx.x;
  if (t < C) {
    float s1 = 0.f, s2 = 0.f;
    for (int ch = 0; ch < NCH; ch++) {
      s1 += stats[((size_t)ch * C + t) * 2];
      s2 += stats[((size_t)ch * C + t) * 2 + 1];
    }
    float m = s1 / n;
    float v = s2 / n - m * m;
    float scale = bnp[t] / sqrtf(v + BNEPS);
    sc[t] = scale;
    sc[64 + t] = bnp[C + t] - m * scale;
  }
  __syncthreads();
  size_t i = (size_t)blockIdx.x * 256 + t;
  if (i < (size_t)n * C) {
    int c = (int)(i % C);
    float v = pre[i] * sc[c] + sc[64 + c];
    post[i] = v > 0.f ? v : 0.f;
  }
}

// ---------------- points_mean ----------------
__global__ void pm_k(const float* __restrict__ vf, const int* __restrict__ c0, int n0,
                     float* __restrict__ pm, float* __restrict__ out1) {
  int i = blockIdx.x * 256 + threadIdx.x;
  if (i >= n0) return;
  float b = (float)c0[(size_t)i * 4];
  float x = vf[(size_t)i * 4], y = vf[(size_t)i * 4 + 1], z = vf[(size_t)i * 4 + 2];
  pm[(size_t)i * 4] = b; pm[(size_t)i * 4 + 1] = x; pm[(size_t)i * 4 + 2] = y; pm[(size_t)i * 4 + 3] = z;
  out1[(size_t)i * 4] = b; out1[(size_t)i * 4 + 1] = x; out1[(size_t)i * 4 + 2] = y; out1[(size_t)i * 4 + 3] = z;
}

// ---------------- knn prep: world coords per known point + batch boundary ----------------
__global__ void knnprep_k(const int* __restrict__ coords, int nl, float vx, float vy, float vz,
                          float4* __restrict__ kp4, int* __restrict__ bs) {
  int i = blockIdx.x * 256 + threadIdx.x;
  if (i >= nl) return;
  const int* c = coords + (size_t)i * 4;
  kp4[i] = make_float4(OFFX + (c[3] + 0.5f) * vx,
                       OFFY + (c[2] + 0.5f) * vy,
                       OFFZ + (c[1] + 0.5f) * vz, (float)c[0]);
  if (c[0] == 0 && (i + 1 == nl || coords[(size_t)(i + 1) * 4] == 1)) bs[0] = i + 1;
}

// ---------------- 3-NN: 4-slot branchless top-3 (ILP), batch-range restricted ----------------
__global__ __launch_bounds__(256) void knn_part_k(const float4* __restrict__ pm4, int n0,
                                                  const float4* __restrict__ kp4, int nl,
                                                  const int* __restrict__ bsp,
                                                  float* __restrict__ pd, int* __restrict__ pi) {
  __shared__ __align__(16) float4 kp[CHUNK];
  int t = threadIdx.x;
  int u = blockIdx.x * 256 + t;
  int bs = bsp[0];
  int per = (nl + KC - 1) / KC;
  int ks = blockIdx.y * per;
  int ke = ks + per; if (ke > nl) ke = nl;
  float ux = 0, uy = 0, uz = 0;
  int lo = 0, hi = 0;
  if (u < n0) {
    float4 up = pm4[u];
    ux = up.y; uy = up.z; uz = up.w;
    lo = (up.x == 0.f) ? 0 : bs;
    hi = (up.x == 0.f) ? bs : nl;
  }
  float ds[4][3]; int is[4][3];
#pragma unroll
  for (int s = 0; s < 4; s++) { ds[s][0] = ds[s][1] = ds[s][2] = 3e38f; is[s][0] = is[s][1] = is[s][2] = -1; }
#define SLOT(S, EE) { \
      float4 q = kp[EE]; \
      float dx = ux - q.x, dy = uy - q.y, dz = uz - q.z; \
      float dd = fmaf(dx, dx, fmaf(dy, dy, dz * dz)); \
      int gi = base + (EE); \
      bool l0 = dd < ds[S][0], l1 = dd < ds[S][1], l2 = dd < ds[S][2]; \
      ds[S][2] = l2 ? (l1 ? ds[S][1] : dd) : ds[S][2]; \
      is[S][2] = l2 ? (l1 ? is[S][1] : gi) : is[S][2]; \
      ds[S][1] = l1 ? (l0 ? ds[S][0] : dd) : ds[S][1]; \
      is[S][1] = l1 ? (l0 ? is[S][0] : gi) : is[S][1]; \
      ds[S][0] = l0 ? dd : ds[S][0]; \
      is[S][0] = l0 ? gi : is[S][0]; }
  for (int base = ks; base < ke; base += CHUNK) {
    int m = ke - base; if (m > CHUNK) m = CHUNK;
    __syncthreads();
    for (int i = t; i < m; i += 256) kp[i] = kp4[base + i];
    __syncthreads();
    int e0 = lo - base; if (e0 < 0) e0 = 0;
    int e1 = hi - base; if (e1 > m) e1 = m;
    int e = e0;
    for (; e + 4 <= e1; e += 4) { SLOT(0, e) SLOT(1, e + 1) SLOT(2, e + 2) SLOT(3, e + 3) }
    for (; e < e1; e++) { SLOT(0, e) }
  }
#undef SLOT
  // merge slots 1..3 into slot 0
#pragma unroll
  for (int s = 1; s < 4; s++)
#pragma unroll
    for (int tt = 0; tt < 3; tt++) {
      float dd = ds[s][tt]; int gi = is[s][tt];
      bool l0 = dd < ds[0][0], l1 = dd < ds[0][1], l2 = dd < ds[0][2];
      ds[0][2] = l2 ? (l1 ? ds[0][1] : dd) : ds[0][2];
      is[0][2] = l2 ? (l1 ? is[0][1] : gi) : is[0][2];
      ds[0][1] = l1 ? (l0 ? ds[0][0] : dd) : ds[0][1];
      is[0][1] = l1 ? (l0 ? is[0][0] : gi) : is[0][1];
      ds[0][0] = l0 ? dd : ds[0][0];
      is[0][0] = l0 ? gi : is[0][0];
    }
  if (u < n0) {
    size_t o = ((size_t)u * KC + blockIdx.y) * 3;
    pd[o] = ds[0][0]; pd[o + 1] = ds[0][1]; pd[o + 2] = ds[0][2];
    pi[o] = is[0][0]; pi[o + 1] = is[0][1]; pi[o + 2] = is[0][2];
  }
}

__global__ void knn_merge_k(const float* __restrict__ pd, const int* __restrict__ pi, int n0,
                            float* __restrict__ wv, int* __restrict__ iv) {
  int u = blockIdx.x * 256 + threadIdx.x;
  if (u >= n0) return;
  float d0 = 3e38f, d1 = 3e38f, d2 = 3e38f;
  int i0 = -1, i1 = -1, i2 = -1;
  for (int c = 0; c < KC; c++) {
    size_t o = ((size_t)u * KC + c) * 3;
    for (int e = 0; e < 3; e++) {
      int gi = pi[o + e];
      if (gi < 0) continue;
      float d = pd[o + e];
      if (d < d2) {
        if (d < d1) {
          if (d < d0) { d2 = d1; i2 = i1; d1 = d0; i1 = i0; d0 = d; i0 = gi; }
          else        { d2 = d1; i2 = i1; d1 = d;  i1 = gi; }
        } else        { d2 = d;  i2 = gi; }
      }
    }
  }
  float w0 = 1.f / (d0 + 1e-8f), w1 = 1.f / (d1 + 1e-8f), w2 = 1.f / (d2 + 1e-8f);
  float s = w0 + w1 + w2;
  wv[(size_t)u * 3] = w0 / s; wv[(size_t)u * 3 + 1] = w1 / s; wv[(size_t)u * 3 + 2] = w2 / s;
  iv[(size_t)u * 3] = i0; iv[(size_t)u * 3 + 1] = i1; iv[(size_t)u * 3 + 2] = i2;
}

__global__ void interp_k(const float* __restrict__ f, int C, const float* __restrict__ wv,
                         const int* __restrict__ iv, int n0, float* __restrict__ X, int xoff) {
  int t = blockIdx.x * 256 + threadIdx.x;
  if (t >= n0 * C) return;
  int u = t / C, c = t % C;
  float r = wv[(size_t)u * 3]     * f[(size_t)iv[(size_t)u * 3]     * C + c]
          + wv[(size_t)u * 3 + 1] * f[(size_t)iv[(size_t)u * 3 + 1] * C + c]
          + wv[(size_t)u * 3 + 2] * f[(size_t)iv[(size_t)u * 3 + 2] * C + c];
  X[(size_t)u * 160 + xoff + c] = r;
}

// ---------------- extra 1x1 conv ----------------
__global__ void conv1x1_k(const float* __restrict__ f, const float* __restrict__ we, int n,
                          float* __restrict__ out) {
  int t = blockIdx.x * 256 + threadIdx.x;
  if (t >= n * 64) return;
  int p = t >> 6, co = t & 63;
  const float* fr = f + (size_t)p * 64;
  float a = 0.f;
#pragma unroll 16
  for (int ci = 0; ci < 64; ci++) a = fmaf(fr[ci], we[ci * 64 + co], a);
  out[t] = a;
}

// ---------------- dense scatter (B, 64*D3, H3, W3) ----------------
__global__ void scatter_k(const float* __restrict__ post, const int* __restrict__ c3, int n3,
                          float* __restrict__ out0) {
  int t = blockIdx.x * 256 + threadIdx.x;
  if (t >= n3 * 64) return;
  int p = t >> 6, c = t & 63;
  const int* cc = c3 + (size_t)p * 4;
  size_t o = ((((size_t)cc[0] * 64 + c) * 6 + cc[1]) * 100 + cc[2]) * 100 + cc[3];
  out0[o] = post[t];
}

// ---------------- head ----------------
__global__ __launch_bounds__(256) void head_k(const float* __restrict__ X,
                                              const float* __restrict__ fcw,
                                              const float* __restrict__ clsw,
                                              const float* __restrict__ regw,
                                              int n0, float* __restrict__ outc,
                                              float* __restrict__ outr) {
  __shared__ float fl[64 * 161];
  int t = threadIdx.x;
  for (int i = t; i < 64 * 160; i += 256) {
    int r = i / 160, c = i % 160;
    fl[r * 161 + c] = fcw[i];
  }
  __syncthreads();
  int wave = t >> 6, lane = t & 63;
  int u = blockIdx.x * 4 + wave;
  if (u >= n0) return;
  const float* xr = X + (size_t)u * 160;
  const float* wr = fl + (size_t)lane * 161;
  float a = 0.f;
#pragma unroll 8
  for (int i = 0; i < 160; i++) a = fmaf(xr[i], wr[i], a);
  float c = a * clsw[lane];
  float r0 = a * regw[lane], r1 = a * regw[64 + lane], r2 = a * regw[128 + lane];
  for (int off = 32; off; off >>= 1) {
    c  += __shfl_down(c, off);
    r0 += __shfl_down(r0, off);
    r1 += __shfl_down(r1, off);
    r2 += __shfl_down(r2, off);
  }
  if (lane == 0) {
    outc[u] = c;
    outr[(size_t)u * 3] = r0; outr[(size_t)u * 3 + 1] = r1; outr[(size_t)u * 3 + 2] = r2;
  }
}

// ---------------- host ----------------
extern "C" void kernel_launch(void* const* d_in, const int* in_sizes, int n_in,
                              void* d_out, int out_size, void* d_ws, size_t ws_size,
                              hipStream_t stream) {
  const float* vf  = (const float*)d_in[0];
  const int* c0 = (const int*)d_in[1];
  const int* c1 = (const int*)d_in[2];
  const int* c2 = (const int*)d_in[3];
  const int* c3 = (const int*)d_in[4];
  const float* w00 = (const float*)d_in[5];  const float* b00 = (const float*)d_in[6];
  const float* w01 = (const float*)d_in[7];  const float* b01 = (const float*)d_in[8];
  const float* wd0 = (const float*)d_in[9];  const float* bd0 = (const float*)d_in[10];
  const float* w10 = (const float*)d_in[11]; const float* b10 = (const float*)d_in[12];
  const float* w11 = (const float*)d_in[13]; const float* b11 = (const float*)d_in[14];
  const float* wd1 = (const float*)d_in[15]; const float* bd1 = (const float*)d_in[16];
  const float* w20 = (const float*)d_in[17]; const float* b20 = (const float*)d_in[18];
  const float* w21 = (const float*)d_in[19]; const float* b21 = (const float*)d_in[20];
  const float* w22 = (const float*)d_in[21]; const float* b22 = (const float*)d_in[22];
  const float* wd2 = (const float*)d_in[23]; const float* bd2 = (const float*)d_in[24];
  const float* w30 = (const float*)d_in[25]; const float* b30 = (const float*)d_in[26];
  const float* w31 = (const float*)d_in[27]; const float* b31 = (const float*)d_in[28];
  const float* w32 = (const float*)d_in[29]; const float* b32 = (const float*)d_in[30];
  const float* we  = (const float*)d_in[31]; const float* be  = (const float*)d_in[32];
  const float* fcw = (const float*)d_in[33];
  const float* clsw = (const float*)d_in[34];
  const float* regw = (const float*)d_in[35];

  int N0 = in_sizes[1] / 4, N1 = in_sizes[2] / 4, N2 = in_sizes[3] / 4, N3 = in_sizes[4] / 4;
  int maxN = N0; if (N1 > maxN) maxN = N1; if (N2 > maxN) maxN = N2; if (N3 > maxN) maxN = N3;

  auto cdiv = [](int a, int b) { return (a + b - 1) / b; };
  char* p = (char*)d_ws;
  auto alloc = [&](size_t bytes) { char* r = p; p += (bytes + 255) & ~(size_t)255; return r; };

  int* keys0 = (int*)alloc((size_t)N0 * 4);
  int* keys1 = (int*)alloc((size_t)N1 * 4);
  int* keys2 = (int*)alloc((size_t)N2 * 4);
  int* keys3 = (int*)alloc((size_t)N3 * 4);
  int* nbr0  = (int*)alloc((size_t)N0 * 27 * 4);
  int* nbrs1 = (int*)alloc((size_t)N1 * 27 * 4);
  int* nbr1  = (int*)alloc((size_t)N1 * 27 * 4);
  int* nbrs2 = (int*)alloc((size_t)N2 * 27 * 4);
  int* nbr2  = (int*)alloc((size_t)N2 * 27 * 4);
  int* nbrs3 = (int*)alloc((size_t)N3 * 27 * 4);
  int* nbr3  = (int*)alloc((size_t)N3 * 27 * 4);
  float* FA = (float*)alloc((size_t)maxN * 64 * 4);
  float* FB = (float*)alloc((size_t)maxN * 64 * 4);
  float* FC = (float*)alloc((size_t)maxN * 64 * 4);
  float* stats = (float*)alloc((size_t)NCH * 64 * 2 * 4);
  float* pd = (float*)alloc((size_t)N0 * KC * 3 * 4);
  int*   pi = (int*)alloc((size_t)N0 * KC * 3 * 4);
  float* wv = (float*)alloc((size_t)N0 * 3 * 4);
  int*   iv = (int*)alloc((size_t)N0 * 3 * 4);
  float* X  = (float*)alloc((size_t)N0 * 160 * 4);
  float* pmb = (float*)alloc((size_t)N0 * 4 * 4);
  float4* kp1 = (float4*)alloc((size_t)N1 * 16);
  float4* kp2 = (float4*)alloc((size_t)N2 * 16);
  float4* kp3 = (float4*)alloc((size_t)N3 * 16);
  int* bsA = (int*)alloc(32);

  float* out0 = (float*)d_out;
  float* out1 = out0 + 7680000;        // points_mean
  float* outc = out1 + (size_t)N0 * 4; // cls
  float* outr = outc + N0;             // reg
  // dense-output region doubles as conv partial-sum scratch until the final memset
  float* partial = out0;  // NG * n * COUT floats needed; max < 7.68M

  keys_k<<<cdiv(N0, 256), 256, 0, stream>>>(c0, N0, 41, 800, 800, keys0);
  keys_k<<<cdiv(N1, 256), 256, 0, stream>>>(c1, N1, 21, 400, 400, keys1);
  keys_k<<<cdiv(N2, 256), 256, 0, stream>>>(c2, N2, 11, 200, 200, keys2);
  keys_k<<<cdiv(N3, 256), 256, 0, stream>>>(c3, N3, 6, 100, 100, keys3);
  nbr_k<<<cdiv(N0 * 27, 256), 256, 0, stream>>>(c0, N0, keys0, N0, 41, 800, 800, 1, nbr0);
  nbr_k<<<cdiv(N1 * 27, 256), 256, 0, stream>>>(c1, N1, keys0, N0, 41, 800, 800, 2, nbrs1);
  nbr_k<<<cdiv(N1 * 27, 256), 256, 0, stream>>>(c1, N1, keys1, N1, 21, 400, 400, 1, nbr1);
  nbr_k<<<cdiv(N2 * 27, 256), 256, 0, stream>>>(c2, N2, keys1, N1, 21, 400, 400, 2, nbrs2);
  nbr_k<<<cdiv(N2 * 27, 256), 256, 0, stream>>>(c2, N2, keys2, N2, 11, 200, 200, 1, nbr2);
  nbr_k<<<cdiv(N3 * 27, 256), 256, 0, stream>>>(c3, N3, keys2, N2, 11, 200, 200, 2, nbrs3);
  nbr_k<<<cdiv(N3 * 27, 256), 256, 0, stream>>>(c3, N3, keys3, N3, 6, 100, 100, 1, nbr3);
  pm_k<<<cdiv(N0, 256), 256, 0, stream>>>(vf, c0, N0, pmb, out1);
  knnprep_k<<<cdiv(N1, 256), 256, 0, stream>>>(c1, N1, 0.2f, 0.2f, 0.4f, kp1, bsA + 0);
  knnprep_k<<<cdiv(N2, 256), 256, 0, stream>>>(c2, N2, 0.4f, 0.4f, 0.8f, kp2, bsA + 1);
  knnprep_k<<<cdiv(N3, 256), 256, 0, stream>>>(c3, N3, 0.8f, 0.8f, 1.6f, kp3, bsA + 2);

  auto conv = [&](const float* fin, const int* nb, const float* wptr, int n, int cin, int cout) {
    dim3 g(cdiv(n, 64), NG);
    int gs = n * cout;
    if (cin == 4 && cout == 16)
      convg_k<4, 16><<<g, 256, 0, stream>>>(fin, nb, wptr, n, partial, gs);
    else if (cin == 16 && cout == 16)
      convg_k<16, 16><<<g, 256, 0, stream>>>(fin, nb, wptr, n, partial, gs);
    else if (cin == 16 && cout == 32)
      convg_k<16, 32><<<g, 256, 0, stream>>>(fin, nb, wptr, n, partial, gs);
    else if (cin == 32 && cout == 32)
      convg_k<32, 32><<<g, 256, 0, stream>>>(fin, nb, wptr, n, partial, gs);
    else if (cin == 32 && cout == 64)
      convg_k<32, 64><<<g, 256, 0, stream>>>(fin, nb, wptr, n, partial, gs);
    else
      convg_k<64, 64><<<g, 256, 0, stream>>>(fin, nb, wptr, n, partial, gs);
  };
  auto bnp = [&](const float* bnpar, int n, int C, float* post) {
    bnpart_k<<<NCH, 256, 0, stream>>>(partial, NG, n * C, n, C, FC, stats);
    bnapply_k<<<cdiv(n * C, 256), 256, 0, stream>>>(FC, stats, bnpar, n, C, post);
  };
  auto knn = [&](const float4* kp4, const int* bsl, int nl, const float* f, int C, int xoff) {
    knn_part_k<<<dim3(cdiv(N0, 256), KC), 256, 0, stream>>>((const float4*)pmb, N0, kp4, nl,
                                                            bsl, pd, pi);
    knn_merge_k<<<cdiv(N0, 256), 256, 0, stream>>>(pd, pi, N0, wv, iv);
    interp_k<<<cdiv(N0 * C, 256), 256, 0, stream>>>(f, C, wv, iv, N0, X, xoff);
  };

  conv(vf, nbr0, w00, N0, 4, 16);   bnp(b00, N0, 16, FA);
  conv(FA, nbr0, w01, N0, 16, 16);  bnp(b01, N0, 16, FB);
  conv(FB, nbrs1, wd0, N1, 16, 32); bnp(bd0, N1, 32, FA);
  conv(FA, nbr1, w10, N1, 32, 32);  bnp(b10, N1, 32, FB);
  conv(FB, nbr1, w11, N1, 32, 32);  bnp(b11, N1, 32, FA);
  knn(kp1, bsA + 0, N1, FA, 32, 0);
  conv(FA, nbrs2, wd1, N2, 32, 64); bnp(bd1, N2, 64, FB);
  conv(FB, nbr2, w20, N2, 64, 64);  bnp(b20, N2, 64, FA);
  conv(FA, nbr2, w21, N2, 64, 64);  bnp(b21, N2, 64, FB);
  conv(FB, nbr2, w22, N2, 64, 64);  bnp(b22, N2, 64, FA);
  knn(kp2, bsA + 1, N2, FA, 64, 32);
  conv(FA, nbrs3, wd2, N3, 64, 64); bnp(bd2, N3, 64, FB);
  conv(FB, nbr3, w30, N3, 64, 64);  bnp(b30, N3, 64, FA);
  conv(FA, nbr3, w31, N3, 64, 64);  bnp(b31, N3, 64, FB);
  conv(FB, nbr3, w32, N3, 64, 64);  bnp(b32, N3, 64, FA);
  knn(kp3, bsA + 2, N3, FA, 64, 96);

  conv1x1_k<<<cdiv(N3 * 64, 256), 256, 0, stream>>>(FA, we, N3, FC);
  bnpart_k<<<NCH, 256, 0, stream>>>(FC, 1, 0, N3, 64, FC, stats);
  bnapply_k<<<cdiv(N3 * 64, 256), 256, 0, stream>>>(FC, stats, be, N3, 64, FB);
  hipMemsetAsync(d_out, 0, (size_t)7680000 * 4, stream);
  scatter_k<<<cdiv(N3 * 64, 256), 256, 0, stream>>>(FB, c3, N3, out0);
  head_k<<<cdiv(N0, 4), 256, 0, stream>>>(X, fcw, clsw, regw, N0, outc, outr);
}

// Round 5
// 1262.563 us; speedup vs baseline: 1.3823x; 1.1408x over previous
//
#include <hip/hip_runtime.h>

#define OFFX 0.0f
#define OFFY -40.0f
#define OFFZ -3.0f
#define BNEPS 1e-3f
#define KC 8      // knn chunks over known points
#define CHUNK 512 // knn LDS chunk (known points)
#define NCH 128   // bn partial chunks
#define NG 9      // conv tap groups (3 taps each)

// ---------------- keys ----------------
__global__ void keys_k(const int* __restrict__ coords, int n, int D, int H, int W,
                       int* __restrict__ keys) {
  int i = blockIdx.x * 256 + threadIdx.x;
  if (i < n) {
    const int* c = coords + (size_t)i * 4;
    keys[i] = ((c[0] * D + c[1]) * H + c[2]) * W + c[3];
  }
}

// ---------------- neighbor tables (subm: scale=1, stride: scale=2) ----------------
__global__ void nbr_k(const int* __restrict__ coords, int np, const int* __restrict__ keys, int nk,
                      int D, int H, int W, int scale, int* __restrict__ nbr) {
  int t = blockIdx.x * 256 + threadIdx.x;
  if (t >= np * 27) return;
  int p = t / 27, k = t % 27;
  int kz = k / 9 - 1, ky = (k / 3) % 3 - 1, kx = k % 3 - 1;
  const int* c = coords + (size_t)p * 4;
  int z = c[1] * scale + kz, y = c[2] * scale + ky, x = c[3] * scale + kx;
  int r = -1;
  if (z >= 0 && z < D && y >= 0 && y < H && x >= 0 && x < W) {
    int q = ((c[0] * D + z) * H + y) * W + x;
    int lo = 0, hi = nk;
    while (lo < hi) { int m = (lo + hi) >> 1; if (keys[m] < q) lo = m + 1; else hi = m; }
    if (lo < nk && keys[lo] == q) r = lo;
  }
  nbr[t] = r;
}

// ---------------- sparse 3x3x3 conv: LDS-staged tile-GEMM, tap-group partials ----------------
// grid = (cdiv(n,64), NG). Per tap: cooperative gather into LDS transposed G[c][p]
// (wave holds r=0..63 at const c4 -> conflict-free writes); register-tile GEMM.
template<int CIN, int COUT>
__global__ __launch_bounds__(256) void convg_k(const float* __restrict__ feats,
                                               const int* __restrict__ nbr,
                                               const float* __restrict__ w, int n,
                                               float* __restrict__ partial, int gstride) {
  constexpr int TP = 64;
  constexpr int LDP = 68;        // row stride: 16B-aligned reads, conflict-free both phases
  constexpr int CO = COUT / 16;  // cols per thread (16 col-groups)
  __shared__ float G[CIN * LDP];
  int tid = threadIdx.x;
  int pg = tid >> 4, cg = tid & 15;
  int p0 = blockIdx.x * TP;
  int k0 = blockIdx.y * 3;
  float acc[4][CO];
#pragma unroll
  for (int i = 0; i < 4; i++)
#pragma unroll
    for (int j = 0; j < CO; j++) acc[i][j] = 0.f;

  for (int kk = 0; kk < 3; kk++) {
    int k = k0 + kk;
    __syncthreads();
    // wave-conflict-free staging: lane r = ch&63 (full wave spans r), c4 = ch>>6 const/wave
    for (int ch = tid; ch < TP * CIN / 4; ch += 256) {
      int r = ch & 63, c4 = ch >> 6;
      int p = p0 + r;
      int idx = (p < n) ? nbr[(size_t)p * 27 + k] : -1;
      float4 fv = make_float4(0.f, 0.f, 0.f, 0.f);
      if (idx >= 0) fv = *(const float4*)(feats + (size_t)idx * CIN + c4 * 4);
      G[(c4 * 4 + 0) * LDP + r] = fv.x;
      G[(c4 * 4 + 1) * LDP + r] = fv.y;
      G[(c4 * 4 + 2) * LDP + r] = fv.z;
      G[(c4 * 4 + 3) * LDP + r] = fv.w;
    }
    __syncthreads();
    const float* wk = w + (size_t)k * CIN * COUT + cg * CO;
#pragma unroll 8
    for (int c = 0; c < CIN; c++) {
      float4 g4 = *(const float4*)&G[c * LDP + pg * 4];
      float wv[CO];
      if constexpr (CO == 4)      *(float4*)wv = *(const float4*)(wk + c * COUT);
      else if constexpr (CO == 2) *(float2*)wv = *(const float2*)(wk + c * COUT);
      else                        wv[0] = wk[c * COUT];
      float gp[4] = {g4.x, g4.y, g4.z, g4.w};
#pragma unroll
      for (int i = 0; i < 4; i++)
#pragma unroll
        for (int j = 0; j < CO; j++) acc[i][j] = fmaf(gp[i], wv[j], acc[i][j]);
    }
  }
#pragma unroll
  for (int i = 0; i < 4; i++) {
    int p = p0 + pg * 4 + i;
    if (p < n) {
      float* dst = partial + (size_t)blockIdx.y * gstride + (size_t)p * COUT + cg * CO;
      if constexpr (CO == 4)      *(float4*)dst = *(float4*)acc[i];
      else if constexpr (CO == 2) *(float2*)dst = *(float2*)acc[i];
      else                        dst[0] = acc[i][0];
    }
  }
}

// ---------------- batchnorm: sum partials + stats, then finalize+apply ----------------
__global__ void bnpart_k(const float* __restrict__ partial, int G, int gstride, int n, int C,
                         float* __restrict__ pre, float* __restrict__ stats) {
  __shared__ float l1[256], l2[256];
  int t = threadIdx.x;
  int total = n * C;
  float s1 = 0.f, s2 = 0.f;
  for (int i = blockIdx.x * 256 + t; i < total; i += NCH * 256) {
    float v = 0.f;
    for (int g = 0; g < G; g++) v += partial[(size_t)g * gstride + i];
    pre[i] = v;
    s1 += v; s2 += v * v;
  }
  l1[t] = s1; l2[t] = s2;
  for (int s = 128; s >= C; s >>= 1) {
    __syncthreads();
    if (t < s) { l1[t] += l1[t + s]; l2[t] += l2[t + s]; }
  }
  __syncthreads();
  if (t < C) {
    stats[((size_t)blockIdx.x * C + t) * 2] = l1[t];
    stats[((size_t)blockIdx.x * C + t) * 2 + 1] = l2[t];
  }
}

__global__ void bnapply_k(const float* __restrict__ pre, const float* __restrict__ stats,
                          const float* __restrict__ bnp, int n, int C, float* __restrict__ post) {
  __shared__ float sc[128];
  int t = threadIdx.x;
  if (t < C) {
    float s1 = 0.f, s2 = 0.f;
    for (int ch = 0; ch < NCH; ch++) {
      s1 += stats[((size_t)ch * C + t) * 2];
      s2 += stats[((size_t)ch * C + t) * 2 + 1];
    }
    float m = s1 / n;
    float v = s2 / n - m * m;
    float scale = bnp[t] / sqrtf(v + BNEPS);
    sc[t] = scale;
    sc[64 + t] = bnp[C + t] - m * scale;
  }
  __syncthreads();
  size_t i = (size_t)blockIdx.x * 256 + t;
  if (i < (size_t)n * C) {
    int c = (int)(i % C);
    float v = pre[i] * sc[c] + sc[64 + c];
    post[i] = v > 0.f ? v : 0.f;
  }
}

// ---------------- points_mean ----------------
__global__ void pm_k(const float* __restrict__ vf, const int* __restrict__ c0, int n0,
                     float* __restrict__ pm, float* __restrict__ out1) {
  int i = blockIdx.x * 256 + threadIdx.x;
  if (i >= n0) return;
  float b = (float)c0[(size_t)i * 4];
  float x = vf[(size_t)i * 4], y = vf[(size_t)i * 4 + 1], z = vf[(size_t)i * 4 + 2];
  pm[(size_t)i * 4] = b; pm[(size_t)i * 4 + 1] = x; pm[(size_t)i * 4 + 2] = y; pm[(size_t)i * 4 + 3] = z;
  out1[(size_t)i * 4] = b; out1[(size_t)i * 4 + 1] = x; out1[(size_t)i * 4 + 2] = y; out1[(size_t)i * 4 + 3] = z;
}

// ---------------- knn prep: world coords per known point + batch boundary ----------------
__global__ void knnprep_k(const int* __restrict__ coords, int nl, float vx, float vy, float vz,
                          float4* __restrict__ kp4, int* __restrict__ bs) {
  int i = blockIdx.x * 256 + threadIdx.x;
  if (i >= nl) return;
  const int* c = coords + (size_t)i * 4;
  kp4[i] = make_float4(OFFX + (c[3] + 0.5f) * vx,
                       OFFY + (c[2] + 0.5f) * vy,
                       OFFZ + (c[1] + 0.5f) * vz, (float)c[0]);
  if (c[0] == 0 && (i + 1 == nl || coords[(size_t)(i + 1) * 4] == 1)) bs[0] = i + 1;
}

// ---------------- 3-NN: 4-slot branchless top-3, SoA partials, batch-range restricted ----------------
__global__ __launch_bounds__(256) void knn_part_k(const float4* __restrict__ pm4, int n0,
                                                  const float4* __restrict__ kp4, int nl,
                                                  const int* __restrict__ bsp,
                                                  float* __restrict__ pd, int* __restrict__ pi) {
  __shared__ __align__(16) float4 kp[CHUNK];
  int t = threadIdx.x;
  int u = blockIdx.x * 256 + t;
  int bs = bsp[0];
  int per = (nl + KC - 1) / KC;
  int ks = blockIdx.y * per;
  int ke = ks + per; if (ke > nl) ke = nl;
  float ux = 0, uy = 0, uz = 0;
  int lo = 0, hi = 0;
  if (u < n0) {
    float4 up = pm4[u];
    ux = up.y; uy = up.z; uz = up.w;
    lo = (up.x == 0.f) ? 0 : bs;
    hi = (up.x == 0.f) ? bs : nl;
  }
  float ds[4][3]; int is[4][3];
#pragma unroll
  for (int s = 0; s < 4; s++) { ds[s][0] = ds[s][1] = ds[s][2] = 3e38f; is[s][0] = is[s][1] = is[s][2] = -1; }
#define SLOT(S, EE) { \
      float4 q = kp[EE]; \
      float dx = ux - q.x, dy = uy - q.y, dz = uz - q.z; \
      float dd = fmaf(dx, dx, fmaf(dy, dy, dz * dz)); \
      int gi = base + (EE); \
      bool l0 = dd < ds[S][0], l1 = dd < ds[S][1], l2 = dd < ds[S][2]; \
      ds[S][2] = l2 ? (l1 ? ds[S][1] : dd) : ds[S][2]; \
      is[S][2] = l2 ? (l1 ? is[S][1] : gi) : is[S][2]; \
      ds[S][1] = l1 ? (l0 ? ds[S][0] : dd) : ds[S][1]; \
      is[S][1] = l1 ? (l0 ? is[S][0] : gi) : is[S][1]; \
      ds[S][0] = l0 ? dd : ds[S][0]; \
      is[S][0] = l0 ? gi : is[S][0]; }
  for (int base = ks; base < ke; base += CHUNK) {
    int m = ke - base; if (m > CHUNK) m = CHUNK;
    __syncthreads();
    for (int i = t; i < m; i += 256) kp[i] = kp4[base + i];
    __syncthreads();
    int e0 = lo - base; if (e0 < 0) e0 = 0;
    int e1 = hi - base; if (e1 > m) e1 = m;
    int e = e0;
    for (; e + 4 <= e1; e += 4) { SLOT(0, e) SLOT(1, e + 1) SLOT(2, e + 2) SLOT(3, e + 3) }
    for (; e < e1; e++) { SLOT(0, e) }
  }
#undef SLOT
#pragma unroll
  for (int s = 1; s < 4; s++)
#pragma unroll
    for (int tt = 0; tt < 3; tt++) {
      float dd = ds[s][tt]; int gi = is[s][tt];
      bool l0 = dd < ds[0][0], l1 = dd < ds[0][1], l2 = dd < ds[0][2];
      ds[0][2] = l2 ? (l1 ? ds[0][1] : dd) : ds[0][2];
      is[0][2] = l2 ? (l1 ? is[0][1] : gi) : is[0][2];
      ds[0][1] = l1 ? (l0 ? ds[0][0] : dd) : ds[0][1];
      is[0][1] = l1 ? (l0 ? is[0][0] : gi) : is[0][1];
      ds[0][0] = l0 ? dd : ds[0][0];
      is[0][0] = l0 ? gi : is[0][0];
    }
  if (u < n0) {
    // SoA: [(chunk*3+e)*n0 + u] -> coalesced writes and merge reads
    size_t b = (size_t)blockIdx.y * 3 * n0 + u;
    pd[b] = ds[0][0]; pd[b + n0] = ds[0][1]; pd[b + 2 * (size_t)n0] = ds[0][2];
    pi[b] = is[0][0]; pi[b + n0] = is[0][1]; pi[b + 2 * (size_t)n0] = is[0][2];
  }
}

__global__ void knn_merge_k(const float* __restrict__ pd, const int* __restrict__ pi, int n0,
                            float* __restrict__ wv, int* __restrict__ iv) {
  int u = blockIdx.x * 256 + threadIdx.x;
  if (u >= n0) return;
  float d0 = 3e38f, d1 = 3e38f, d2 = 3e38f;
  int i0 = -1, i1 = -1, i2 = -1;
  for (int c = 0; c < KC * 3; c++) {
    int gi = pi[(size_t)c * n0 + u];
    if (gi < 0) continue;
    float d = pd[(size_t)c * n0 + u];
    if (d < d2) {
      if (d < d1) {
        if (d < d0) { d2 = d1; i2 = i1; d1 = d0; i1 = i0; d0 = d; i0 = gi; }
        else        { d2 = d1; i2 = i1; d1 = d;  i1 = gi; }
      } else        { d2 = d;  i2 = gi; }
    }
  }
  float w0 = 1.f / (d0 + 1e-8f), w1 = 1.f / (d1 + 1e-8f), w2 = 1.f / (d2 + 1e-8f);
  float s = w0 + w1 + w2;
  wv[(size_t)u * 3] = w0 / s; wv[(size_t)u * 3 + 1] = w1 / s; wv[(size_t)u * 3 + 2] = w2 / s;
  iv[(size_t)u * 3] = i0; iv[(size_t)u * 3 + 1] = i1; iv[(size_t)u * 3 + 2] = i2;
}

__global__ void interp_k(const float* __restrict__ f, int C, const float* __restrict__ wv,
                         const int* __restrict__ iv, int n0, float* __restrict__ X, int xoff) {
  int t = blockIdx.x * 256 + threadIdx.x;
  if (t >= n0 * C) return;
  int u = t / C, c = t % C;
  float r = wv[(size_t)u * 3]     * f[(size_t)iv[(size_t)u * 3]     * C + c]
          + wv[(size_t)u * 3 + 1] * f[(size_t)iv[(size_t)u * 3 + 1] * C + c]
          + wv[(size_t)u * 3 + 2] * f[(size_t)iv[(size_t)u * 3 + 2] * C + c];
  X[(size_t)u * 160 + xoff + c] = r;
}

// ---------------- extra 1x1 conv ----------------
__global__ void conv1x1_k(const float* __restrict__ f, const float* __restrict__ we, int n,
                          float* __restrict__ out) {
  int t = blockIdx.x * 256 + threadIdx.x;
  if (t >= n * 64) return;
  int p = t >> 6, co = t & 63;
  const float* fr = f + (size_t)p * 64;
  float a = 0.f;
#pragma unroll 16
  for (int ci = 0; ci < 64; ci++) a = fmaf(fr[ci], we[ci * 64 + co], a);
  out[t] = a;
}

// ---------------- dense scatter (B, 64*D3, H3, W3) ----------------
__global__ void scatter_k(const float* __restrict__ post, const int* __restrict__ c3, int n3,
                          float* __restrict__ out0) {
  int t = blockIdx.x * 256 + threadIdx.x;
  if (t >= n3 * 64) return;
  int p = t >> 6, c = t & 63;
  const int* cc = c3 + (size_t)p * 4;
  size_t o = ((((size_t)cc[0] * 64 + c) * 6 + cc[1]) * 100 + cc[2]) * 100 + cc[3];
  out0[o] = post[t];
}

// ---------------- head ----------------
__global__ __launch_bounds__(256) void head_k(const float* __restrict__ X,
                                              const float* __restrict__ fcw,
                                              const float* __restrict__ clsw,
                                              const float* __restrict__ regw,
                                              int n0, float* __restrict__ outc,
                                              float* __restrict__ outr) {
  __shared__ float fl[64 * 161];
  int t = threadIdx.x;
  for (int i = t; i < 64 * 160; i += 256) {
    int r = i / 160, c = i % 160;
    fl[r * 161 + c] = fcw[i];
  }
  __syncthreads();
  int wave = t >> 6, lane = t & 63;
  int u = blockIdx.x * 4 + wave;
  if (u >= n0) return;
  const float* xr = X + (size_t)u * 160;
  const float* wr = fl + (size_t)lane * 161;
  float a = 0.f;
#pragma unroll 8
  for (int i = 0; i < 160; i++) a = fmaf(xr[i], wr[i], a);
  float c = a * clsw[lane];
  float r0 = a * regw[lane], r1 = a * regw[64 + lane], r2 = a * regw[128 + lane];
  for (int off = 32; off; off >>= 1) {
    c  += __shfl_down(c, off);
    r0 += __shfl_down(r0, off);
    r1 += __shfl_down(r1, off);
    r2 += __shfl_down(r2, off);
  }
  if (lane == 0) {
    outc[u] = c;
    outr[(size_t)u * 3] = r0; outr[(size_t)u * 3 + 1] = r1; outr[(size_t)u * 3 + 2] = r2;
  }
}

// ---------------- host ----------------
extern "C" void kernel_launch(void* const* d_in, const int* in_sizes, int n_in,
                              void* d_out, int out_size, void* d_ws, size_t ws_size,
                              hipStream_t stream) {
  const float* vf  = (const float*)d_in[0];
  const int* c0 = (const int*)d_in[1];
  const int* c1 = (const int*)d_in[2];
  const int* c2 = (const int*)d_in[3];
  const int* c3 = (const int*)d_in[4];
  const float* w00 = (const float*)d_in[5];  const float* b00 = (const float*)d_in[6];
  const float* w01 = (const float*)d_in[7];  const float* b01 = (const float*)d_in[8];
  const float* wd0 = (const float*)d_in[9];  const float* bd0 = (const float*)d_in[10];
  const float* w10 = (const float*)d_in[11]; const float* b10 = (const float*)d_in[12];
  const float* w11 = (const float*)d_in[13]; const float* b11 = (const float*)d_in[14];
  const float* wd1 = (const float*)d_in[15]; const float* bd1 = (const float*)d_in[16];
  const float* w20 = (const float*)d_in[17]; const float* b20 = (const float*)d_in[18];
  const float* w21 = (const float*)d_in[19]; const float* b21 = (const float*)d_in[20];
  const float* w22 = (const float*)d_in[21]; const float* b22 = (const float*)d_in[22];
  const float* wd2 = (const float*)d_in[23]; const float* bd2 = (const float*)d_in[24];
  const float* w30 = (const float*)d_in[25]; const float* b30 = (const float*)d_in[26];
  const float* w31 = (const float*)d_in[27]; const float* b31 = (const float*)d_in[28];
  const float* w32 = (const float*)d_in[29]; const float* b32 = (const float*)d_in[30];
  const float* we  = (const float*)d_in[31]; const float* be  = (const float*)d_in[32];
  const float* fcw = (const float*)d_in[33];
  const float* clsw = (const float*)d_in[34];
  const float* regw = (const float*)d_in[35];

  int N0 = in_sizes[1] / 4, N1 = in_sizes[2] / 4, N2 = in_sizes[3] / 4, N3 = in_sizes[4] / 4;
  int maxN = N0; if (N1 > maxN) maxN = N1; if (N2 > maxN) maxN = N2; if (N3 > maxN) maxN = N3;

  auto cdiv = [](int a, int b) { return (a + b - 1) / b; };
  char* p = (char*)d_ws;
  auto alloc = [&](size_t bytes) { char* r = p; p += (bytes + 255) & ~(size_t)255; return r; };

  int* keys0 = (int*)alloc((size_t)N0 * 4);
  int* keys1 = (int*)alloc((size_t)N1 * 4);
  int* keys2 = (int*)alloc((size_t)N2 * 4);
  int* keys3 = (int*)alloc((size_t)N3 * 4);
  int* nbr0  = (int*)alloc((size_t)N0 * 27 * 4);
  int* nbrs1 = (int*)alloc((size_t)N1 * 27 * 4);
  int* nbr1  = (int*)alloc((size_t)N1 * 27 * 4);
  int* nbrs2 = (int*)alloc((size_t)N2 * 27 * 4);
  int* nbr2  = (int*)alloc((size_t)N2 * 27 * 4);
  int* nbrs3 = (int*)alloc((size_t)N3 * 27 * 4);
  int* nbr3  = (int*)alloc((size_t)N3 * 27 * 4);
  float* FA = (float*)alloc((size_t)maxN * 64 * 4);
  float* FB = (float*)alloc((size_t)maxN * 64 * 4);
  float* FC = (float*)alloc((size_t)maxN * 64 * 4);
  float* stats = (float*)alloc((size_t)NCH * 64 * 2 * 4);
  float* pd = (float*)alloc((size_t)N0 * KC * 3 * 4);
  int*   pi = (int*)alloc((size_t)N0 * KC * 3 * 4);
  float* wv = (float*)alloc((size_t)N0 * 3 * 4);
  int*   iv = (int*)alloc((size_t)N0 * 3 * 4);
  float* X  = (float*)alloc((size_t)N0 * 160 * 4);
  float* pmb = (float*)alloc((size_t)N0 * 4 * 4);
  float4* kp1 = (float4*)alloc((size_t)N1 * 16);
  float4* kp2 = (float4*)alloc((size_t)N2 * 16);
  float4* kp3 = (float4*)alloc((size_t)N3 * 16);
  int* bsA = (int*)alloc(32);

  float* out0 = (float*)d_out;
  float* out1 = out0 + 7680000;        // points_mean
  float* outc = out1 + (size_t)N0 * 4; // cls
  float* outr = outc + N0;             // reg
  // dense-output region doubles as conv partial-sum scratch until the final memset
  float* partial = out0;  // NG * n * COUT floats needed; max < 7.68M

  keys_k<<<cdiv(N0, 256), 256, 0, stream>>>(c0, N0, 41, 800, 800, keys0);
  keys_k<<<cdiv(N1, 256), 256, 0, stream>>>(c1, N1, 21, 400, 400, keys1);
  keys_k<<<cdiv(N2, 256), 256, 0, stream>>>(c2, N2, 11, 200, 200, keys2);
  keys_k<<<cdiv(N3, 256), 256, 0, stream>>>(c3, N3, 6, 100, 100, keys3);
  nbr_k<<<cdiv(N0 * 27, 256), 256, 0, stream>>>(c0, N0, keys0, N0, 41, 800, 800, 1, nbr0);
  nbr_k<<<cdiv(N1 * 27, 256), 256, 0, stream>>>(c1, N1, keys0, N0, 41, 800, 800, 2, nbrs1);
  nbr_k<<<cdiv(N1 * 27, 256), 256, 0, stream>>>(c1, N1, keys1, N1, 21, 400, 400, 1, nbr1);
  nbr_k<<<cdiv(N2 * 27, 256), 256, 0, stream>>>(c2, N2, keys1, N1, 21, 400, 400, 2, nbrs2);
  nbr_k<<<cdiv(N2 * 27, 256), 256, 0, stream>>>(c2, N2, keys2, N2, 11, 200, 200, 1, nbr2);
  nbr_k<<<cdiv(N3 * 27, 256), 256, 0, stream>>>(c3, N3, keys2, N2, 11, 200, 200, 2, nbrs3);
  nbr_k<<<cdiv(N3 * 27, 256), 256, 0, stream>>>(c3, N3, keys3, N3, 6, 100, 100, 1, nbr3);
  pm_k<<<cdiv(N0, 256), 256, 0, stream>>>(vf, c0, N0, pmb, out1);
  knnprep_k<<<cdiv(N1, 256), 256, 0, stream>>>(c1, N1, 0.2f, 0.2f, 0.4f, kp1, bsA + 0);
  knnprep_k<<<cdiv(N2, 256), 256, 0, stream>>>(c2, N2, 0.4f, 0.4f, 0.8f, kp2, bsA + 1);
  knnprep_k<<<cdiv(N3, 256), 256, 0, stream>>>(c3, N3, 0.8f, 0.8f, 1.6f, kp3, bsA + 2);

  auto conv = [&](const float* fin, const int* nb, const float* wptr, int n, int cin, int cout) {
    dim3 g(cdiv(n, 64), NG);
    int gs = n * cout;
    if (cin == 4 && cout == 16)
      convg_k<4, 16><<<g, 256, 0, stream>>>(fin, nb, wptr, n, partial, gs);
    else if (cin == 16 && cout == 16)
      convg_k<16, 16><<<g, 256, 0, stream>>>(fin, nb, wptr, n, partial, gs);
    else if (cin == 16 && cout == 32)
      convg_k<16, 32><<<g, 256, 0, stream>>>(fin, nb, wptr, n, partial, gs);
    else if (cin == 32 && cout == 32)
      convg_k<32, 32><<<g, 256, 0, stream>>>(fin, nb, wptr, n, partial, gs);
    else if (cin == 32 && cout == 64)
      convg_k<32, 64><<<g, 256, 0, stream>>>(fin, nb, wptr, n, partial, gs);
    else
      convg_k<64, 64><<<g, 256, 0, stream>>>(fin, nb, wptr, n, partial, gs);
  };
  auto bnp = [&](const float* bnpar, int n, int C, float* post) {
    bnpart_k<<<NCH, 256, 0, stream>>>(partial, NG, n * C, n, C, FC, stats);
    bnapply_k<<<cdiv(n * C, 256), 256, 0, stream>>>(FC, stats, bnpar, n, C, post);
  };
  auto knn = [&](const float4* kp4, const int* bsl, int nl, const float* f, int C, int xoff) {
    knn_part_k<<<dim3(cdiv(N0, 256), KC), 256, 0, stream>>>((const float4*)pmb, N0, kp4, nl,
                                                            bsl, pd, pi);
    knn_merge_k<<<cdiv(N0, 256), 256, 0, stream>>>(pd, pi, N0, wv, iv);
    interp_k<<<cdiv(N0 * C, 256), 256, 0, stream>>>(f, C, wv, iv, N0, X, xoff);
  };

  conv(vf, nbr0, w00, N0, 4, 16);   bnp(b00, N0, 16, FA);
  conv(FA, nbr0, w01, N0, 16, 16);  bnp(b01, N0, 16, FB);
  conv(FB, nbrs1, wd0, N1, 16, 32); bnp(bd0, N1, 32, FA);
  conv(FA, nbr1, w10, N1, 32, 32);  bnp(b10, N1, 32, FB);
  conv(FB, nbr1, w11, N1, 32, 32);  bnp(b11, N1, 32, FA);
  knn(kp1, bsA + 0, N1, FA, 32, 0);
  conv(FA, nbrs2, wd1, N2, 32, 64); bnp(bd1, N2, 64, FB);
  conv(FB, nbr2, w20, N2, 64, 64);  bnp(b20, N2, 64, FA);
  conv(FA, nbr2, w21, N2, 64, 64);  bnp(b21, N2, 64, FB);
  conv(FB, nbr2, w22, N2, 64, 64);  bnp(b22, N2, 64, FA);
  knn(kp2, bsA + 1, N2, FA, 64, 32);
  conv(FA, nbrs3, wd2, N3, 64, 64); bnp(bd2, N3, 64, FB);
  conv(FB, nbr3, w30, N3, 64, 64);  bnp(b30, N3, 64, FA);
  conv(FA, nbr3, w31, N3, 64, 64);  bnp(b31, N3, 64, FB);
  conv(FB, nbr3, w32, N3, 64, 64);  bnp(b32, N3, 64, FA);
  knn(kp3, bsA + 2, N3, FA, 64, 96);

  conv1x1_k<<<cdiv(N3 * 64, 256), 256, 0, stream>>>(FA, we, N3, FC);
  bnpart_k<<<NCH, 256, 0, stream>>>(FC, 1, 0, N3, 64, FC, stats);
  bnapply_k<<<cdiv(N3 * 64, 256), 256, 0, stream>>>(FC, stats, be, N3, 64, FB);
  hipMemsetAsync(d_out, 0, (size_t)7680000 * 4, stream);
  scatter_k<<<cdiv(N3 * 64, 256), 256, 0, stream>>>(FB, c3, N3, out0);
  head_k<<<cdiv(N0, 4), 256, 0, stream>>>(X, fcw, clsw, regw, N0, outc, outr);
}